// Round 1
// baseline (87.544 us; speedup 1.0000x reference)
//
#include <hip/hip_runtime.h>
#include <math.h>

namespace {
constexpr int N = 512;
constexpr int DIN = 128;
constexpr int PROJ = 128;
constexpr int H = 4;
constexpr int E = 32;       // per-head dim
constexpr int KF = 64;      // ENC/2 frequencies
constexpr int FEAT = E + 2*KF; // 160: [k | cos | sin] / [q | P | Q]
constexpr float SCALE = 0.17677669529663687f; // 1/sqrt(32)
}

__device__ __forceinline__ float warp_red_max(float v) {
  #pragma unroll
  for (int o = 32; o > 0; o >>= 1) v = fmaxf(v, __shfl_xor(v, o, 64));
  return v;
}
__device__ __forceinline__ float warp_red_sum(float v) {
  #pragma unroll
  for (int o = 32; o > 0; o >>= 1) v += __shfl_xor(v, o, 64);
  return v;
}

// One block per row i (128 threads). Computes q,k,v,qt projections for the row,
// u = Wt·qt per head, the sin/cos row features, and the rank-160 A/B features.
__global__ __launch_bounds__(128)
void prep_kernel(const float* __restrict__ inp, const float* __restrict__ pos,
                 const float* __restrict__ f,
                 const float* __restrict__ Wq, const float* __restrict__ bq,
                 const float* __restrict__ Wk, const float* __restrict__ bk,
                 const float* __restrict__ Wv, const float* __restrict__ bv,
                 const float* __restrict__ Wqt, const float* __restrict__ bqt,
                 const float* __restrict__ Wt, const float* __restrict__ bt,
                 float* __restrict__ Afeat, float* __restrict__ Bfeat,
                 float* __restrict__ Vmat, float* __restrict__ c0)
{
  const int i = blockIdx.x;
  const int t = threadIdx.x;   // 0..127
  __shared__ float x[DIN];
  __shared__ float qt_row[PROJ];
  __shared__ float ss[KF], sc[KF];
  __shared__ float u[H][PROJ];

  x[t] = inp[i*DIN + t];
  __syncthreads();

  // thread t computes output column t of all four projections
  float aq = bq[t], ak = bk[t], av = bv[t], aqt = bqt[t];
  #pragma unroll 4
  for (int d = 0; d < DIN; ++d) {
    const float xv = x[d];
    aq  += xv * Wq [d*PROJ + t];
    ak  += xv * Wk [d*PROJ + t];
    av  += xv * Wv [d*PROJ + t];
    aqt += xv * Wqt[d*PROJ + t];
  }
  const int h = t >> 5, e = t & 31;
  Afeat[(h*N + i)*FEAT + e] = aq;   // q part of A
  Bfeat[(h*N + i)*FEAT + e] = ak;   // k part of B
  Vmat [(h*N + i)*E + e]    = av;
  qt_row[t] = aqt;
  if (t < KF) {
    float s, c;
    sincosf(pos[i] * f[t], &s, &c);
    ss[t] = s; sc[t] = c;
  }
  __syncthreads();

  // u[hh][c] = sum_e Wt[c, hh*E+e] * qt[hh*E+e]   (c = t)
  #pragma unroll
  for (int hh = 0; hh < H; ++hh) {
    float acc = 0.f;
    const float* wr = &Wt[t*PROJ + hh*E];
    const float* qr = &qt_row[hh*E];
    #pragma unroll 8
    for (int e2 = 0; e2 < E; ++e2) acc += wr[e2] * qr[e2];
    u[hh][t] = acc;
  }
  if (t < H) {  // c0[h,i] = bt[h*E:]·qt[h*E:]
    float acc = 0.f;
    for (int e2 = 0; e2 < E; ++e2) acc += bt[t*E + e2] * qt_row[t*E + e2];
    c0[t*N + i] = acc;
  }
  if (t < KF) { // B-side trig features (same for every head)
    #pragma unroll
    for (int hh = 0; hh < H; ++hh) {
      Bfeat[(hh*N + i)*FEAT + E + t]      = sc[t]; // cos
      Bfeat[(hh*N + i)*FEAT + E + KF + t] = ss[t]; // sin
    }
  }
  __syncthreads();

  // A-side: P = u0*sin + u1*cos (pairs with cos_j), Q = -u0*cos + u1*sin (pairs with sin_j)
  {
    const int k = t & 63, h0 = t >> 6;
    #pragma unroll
    for (int hh = h0; hh < H; hh += 2) {
      const float u0 = u[hh][2*k], u1 = u[hh][2*k + 1];
      Afeat[(hh*N + i)*FEAT + E + k]      =  u0*ss[k] + u1*sc[k];
      Afeat[(hh*N + i)*FEAT + E + KF + k] = -u0*sc[k] + u1*ss[k];
    }
  }
}

// One block per (row i, head h). Masked score row (160-dot), softmax, out = w·V.
__global__ __launch_bounds__(256)
void attn_kernel(const float* __restrict__ Afeat, const float* __restrict__ Bfeat,
                 const float* __restrict__ Vmat, const float* __restrict__ c0,
                 float* __restrict__ out)
{
  const int i = blockIdx.x, h = blockIdx.y;
  const int t = threadIdx.x;  // 0..255
  __shared__ float Arow[FEAT];
  __shared__ float w[N];
  __shared__ float red[4];
  __shared__ float obuf[8*32];

  if (t < FEAT) Arow[t] = Afeat[(h*N + i)*FEAT + t];
  __syncthreads();

  const float bias = c0[h*N + i];
  const int nj = i + 1;
  const int j0 = t, j1 = t + 256;
  const bool has0 = (j0 < nj), has1 = (j1 < nj);

  float acc0 = 0.f, acc1 = 0.f;
  if (has1) {
    const float4* B0 = (const float4*)&Bfeat[(h*N + j0)*FEAT];
    const float4* B1 = (const float4*)&Bfeat[(h*N + j1)*FEAT];
    #pragma unroll 8
    for (int d = 0; d < FEAT/4; ++d) {
      const float4 a  = *(const float4*)&Arow[4*d];
      const float4 b0 = B0[d];
      const float4 b1 = B1[d];
      acc0 += a.x*b0.x + a.y*b0.y + a.z*b0.z + a.w*b0.w;
      acc1 += a.x*b1.x + a.y*b1.y + a.z*b1.z + a.w*b1.w;
    }
  } else if (has0) {
    const float4* B0 = (const float4*)&Bfeat[(h*N + j0)*FEAT];
    #pragma unroll 8
    for (int d = 0; d < FEAT/4; ++d) {
      const float4 a  = *(const float4*)&Arow[4*d];
      const float4 b0 = B0[d];
      acc0 += a.x*b0.x + a.y*b0.y + a.z*b0.z + a.w*b0.w;
    }
  }

  float mymax = -INFINITY;
  if (has0) { const float s = (acc0 + bias)*SCALE; w[j0] = s; mymax = fmaxf(mymax, s); }
  if (has1) { const float s = (acc1 + bias)*SCALE; w[j1] = s; mymax = fmaxf(mymax, s); }

  float v = warp_red_max(mymax);
  if ((t & 63) == 0) red[t >> 6] = v;
  __syncthreads();
  const float gmax = fmaxf(fmaxf(red[0], red[1]), fmaxf(red[2], red[3]));
  __syncthreads();

  float mysum = 0.f;
  if (has0) { const float e0 = __expf(w[j0] - gmax); w[j0] = e0; mysum += e0; }
  if (has1) { const float e1 = __expf(w[j1] - gmax); w[j1] = e1; mysum += e1; }
  float sv = warp_red_sum(mysum);
  if ((t & 63) == 0) red[t >> 6] = sv;
  __syncthreads();
  const float gsum = red[0] + red[1] + red[2] + red[3];

  // out[h,i,e] = sum_j w[j] * V[h,j,e] / gsum
  const int e = t & 31, g = t >> 5;
  float oacc = 0.f;
  for (int j = g; j < nj; j += 8) oacc += w[j] * Vmat[(h*N + j)*E + e];
  obuf[g*32 + e] = oacc;
  __syncthreads();
  if (t < 32) {
    float tot = 0.f;
    #pragma unroll
    for (int g2 = 0; g2 < 8; ++g2) tot += obuf[g2*32 + t];
    out[i*PROJ + h*E + t] = tot / gsum;
  }
}

extern "C" void kernel_launch(void* const* d_in, const int* in_sizes, int n_in,
                              void* d_out, int out_size, void* d_ws, size_t ws_size,
                              hipStream_t stream) {
  const float* inp = (const float*)d_in[0];
  const float* pos = (const float*)d_in[1];
  const float* f   = (const float*)d_in[2];
  const float* Wq  = (const float*)d_in[3];
  const float* bq  = (const float*)d_in[4];
  const float* Wk  = (const float*)d_in[5];
  const float* bk  = (const float*)d_in[6];
  const float* Wv  = (const float*)d_in[7];
  const float* bv  = (const float*)d_in[8];
  const float* Wqt = (const float*)d_in[9];
  const float* bqt = (const float*)d_in[10];
  const float* Wt  = (const float*)d_in[11];
  const float* bt  = (const float*)d_in[12];
  float* out = (float*)d_out;

  float* ws    = (float*)d_ws;
  float* Afeat = ws;                       // H*N*FEAT
  float* Bfeat = Afeat + H*N*FEAT;         // H*N*FEAT
  float* Vmat  = Bfeat + H*N*FEAT;         // H*N*E
  float* c0    = Vmat + H*N*E;             // H*N

  prep_kernel<<<N, 128, 0, stream>>>(inp, pos, f, Wq, bq, Wk, bk, Wv, bv,
                                     Wqt, bqt, Wt, bt, Afeat, Bfeat, Vmat, c0);
  attn_kernel<<<dim3(N, H), 256, 0, stream>>>(Afeat, Bfeat, Vmat, c0, out);
}

// Round 2
// 61.665 us; speedup vs baseline: 1.4197x; 1.4197x over previous
//
#include <hip/hip_runtime.h>
#include <math.h>

namespace {
constexpr int N = 512;
constexpr int DIN = 128;
constexpr int PROJ = 128;
constexpr int H = 4;
constexpr int E = 32;          // per-head dim
constexpr int KF = 64;         // ENC/2 frequencies
constexpr int FEAT = E + 2*KF; // 160 features: [qk | cos/P | sin/Q]
constexpr float SCALE = 0.17677669529663687f; // 1/sqrt(32)
constexpr int TI = 8;          // i-rows per attn block
}

__device__ __forceinline__ float wave_max(float v) {
  #pragma unroll
  for (int o = 32; o > 0; o >>= 1) v = fmaxf(v, __shfl_xor(v, o, 64));
  return v;
}
__device__ __forceinline__ float wave_sum(float v) {
  #pragma unroll
  for (int o = 32; o > 0; o >>= 1) v += __shfl_xor(v, o, 64);
  return v;
}

// ---- kernel 0: transpose Wt (128x128) so prep's u-matvec reads coalesced ----
__global__ __launch_bounds__(256)
void transpose_wt(const float* __restrict__ Wt, float* __restrict__ WtT) {
  const int idx = blockIdx.x * 256 + threadIdx.x;   // 0..16383
  const int c = idx >> 7, p = idx & 127;            // read Wt[c][p] coalesced
  WtT[p * PROJ + c] = Wt[idx];
}

// ---- kernel 1: per-row features. 2 rows per block, 128 threads ----
__global__ __launch_bounds__(128)
void prep_kernel(const float* __restrict__ inp, const float* __restrict__ pos,
                 const float* __restrict__ f,
                 const float* __restrict__ Wq, const float* __restrict__ bq,
                 const float* __restrict__ Wk, const float* __restrict__ bk,
                 const float* __restrict__ Wv, const float* __restrict__ bv,
                 const float* __restrict__ Wqt, const float* __restrict__ bqt,
                 const float* __restrict__ WtT, const float* __restrict__ bt,
                 float* __restrict__ Afeat, float* __restrict__ BT,
                 float* __restrict__ Vmat, float* __restrict__ c0)
{
  const int i0 = blockIdx.x * 2;
  const int t = threadIdx.x;   // 0..127
  __shared__ float x[2][DIN];
  __shared__ float qt_l[2][PROJ];
  __shared__ float ss[2][KF], sc[2][KF];
  __shared__ float u_l[2][H][PROJ];

  x[0][t] = inp[i0 * DIN + t];
  x[1][t] = inp[(i0 + 1) * DIN + t];
  {
    const int r = t >> 6, k = t & 63;
    float s, c;
    sincosf(pos[i0 + r] * f[k], &s, &c);
    ss[r][k] = s; sc[r][k] = c;
  }
  __syncthreads();

  // thread t owns output column t of the four projections, both rows
  float aq0 = bq[t], aq1 = aq0, ak0 = bk[t], ak1 = ak0;
  float av0 = bv[t], av1 = av0, at0 = bqt[t], at1 = at0;
  #pragma unroll 4
  for (int d = 0; d < DIN; ++d) {
    const float x0 = x[0][d], x1 = x[1][d];
    const float wq = Wq[d*PROJ + t], wk = Wk[d*PROJ + t];
    const float wv = Wv[d*PROJ + t], wt = Wqt[d*PROJ + t];
    aq0 += x0*wq; aq1 += x1*wq;
    ak0 += x0*wk; ak1 += x1*wk;
    av0 += x0*wv; av1 += x1*wv;
    at0 += x0*wt; at1 += x1*wt;
  }
  const int h = t >> 5, e = t & 31;
  Afeat[(h*N + i0    )*FEAT + e] = aq0;
  Afeat[(h*N + i0 + 1)*FEAT + e] = aq1;
  BT[(size_t)(h*FEAT + e)*N + i0    ] = ak0;
  BT[(size_t)(h*FEAT + e)*N + i0 + 1] = ak1;
  Vmat[(h*N + i0    )*E + e] = av0;
  Vmat[(h*N + i0 + 1)*E + e] = av1;
  qt_l[0][t] = at0; qt_l[1][t] = at1;
  __syncthreads();

  // u[r][hh][c] = sum_e WtT[hh*E+e][c] * qt[r][hh*E+e]   (c = t, coalesced)
  #pragma unroll
  for (int hh = 0; hh < H; ++hh) {
    float u0 = 0.f, u1 = 0.f;
    #pragma unroll 4
    for (int e2 = 0; e2 < E; ++e2) {
      const float w = WtT[(hh*E + e2)*PROJ + t];
      u0 += w * qt_l[0][hh*E + e2];
      u1 += w * qt_l[1][hh*E + e2];
    }
    u_l[0][hh][t] = u0; u_l[1][hh][t] = u1;
  }
  if (t < 8) {  // c0[h,i] = bt[h*E:]·qt[h*E:]
    const int r = t >> 2, hh = t & 3;
    float acc = 0.f;
    for (int e2 = 0; e2 < E; ++e2) acc += bt[hh*E + e2] * qt_l[r][hh*E + e2];
    c0[hh*N + i0 + r] = acc;
  }
  __syncthreads();

  // A-side P/Q features + B-side trig features
  {
    const int k = t & 63, h0 = t >> 6;
    #pragma unroll
    for (int r = 0; r < 2; ++r) {
      for (int hh = h0; hh < H; hh += 2) {
        const float u0 = u_l[r][hh][2*k], u1 = u_l[r][hh][2*k + 1];
        Afeat[(hh*N + i0 + r)*FEAT + E + k]      =  u0*ss[r][k] + u1*sc[r][k];
        Afeat[(hh*N + i0 + r)*FEAT + E + KF + k] = -u0*sc[r][k] + u1*ss[r][k];
        BT[(size_t)(hh*FEAT + E + k)*N      + i0 + r] = sc[r][k];
        BT[(size_t)(hh*FEAT + E + KF + k)*N + i0 + r] = ss[r][k];
      }
    }
  }
}

// ---- kernel 2: scores + softmax + PV for an 8-row i-tile of one head ----
__global__ __launch_bounds__(256)
void attn_kernel(const float* __restrict__ Afeat, const float* __restrict__ BT,
                 const float* __restrict__ Vmat, const float* __restrict__ c0,
                 float* __restrict__ out)
{
  const int i0 = blockIdx.x * TI;
  const int h  = blockIdx.y;
  const int t  = threadIdx.x;      // 0..255
  const int jmax = i0 + TI;        // valid columns: j < jmax

  __shared__ float As[TI][FEAT];     // 5 KB
  __shared__ float c0r[TI];
  __shared__ float wT[N][12];        // padded row of 8 weights (24 KB)
  __shared__ float redm[4][TI], reds[4][TI];
  __shared__ float gm[TI], gs[TI];
  __shared__ float obuf[8][TI][32];  // [group][row][e] 8 KB

  // stage A rows (contiguous for this head/tile)
  {
    const float4* src = (const float4*)&Afeat[(size_t)(h*N + i0)*FEAT];
    for (int idx = t; idx < TI*FEAT/4; idx += 256) ((float4*)As)[idx] = src[idx];
  }
  if (t < TI) c0r[t] = c0[h*N + i0 + t];
  __syncthreads();

  const int j0 = 2*t, j1 = 2*t + 1; // jmax is even, so j1 valid whenever j0 is
  float acc0[TI], acc1[TI];
  #pragma unroll
  for (int r = 0; r < TI; ++r) { acc0[r] = 0.f; acc1[r] = 0.f; }

  if (j0 < jmax) {
    const float* Bh = BT + (size_t)h*FEAT*N + j0;
    // software-pipelined (depth 2) over 4-feature groups
    float2 a0, a1, a2, a3, b0, b1, b2, b3;
    #define LDG(g0,g1,g2,g3,dd) \
      g0 = *(const float2*)&Bh[(dd+0)*N]; g1 = *(const float2*)&Bh[(dd+1)*N]; \
      g2 = *(const float2*)&Bh[(dd+2)*N]; g3 = *(const float2*)&Bh[(dd+3)*N];
    #define FMAS(g0,g1,g2,g3,dd) \
      _Pragma("unroll") \
      for (int r = 0; r < TI; ++r) { \
        const float4 a = *(const float4*)&As[r][dd]; \
        acc0[r] += a.x*g0.x + a.y*g1.x + a.z*g2.x + a.w*g3.x; \
        acc1[r] += a.x*g0.y + a.y*g1.y + a.z*g2.y + a.w*g3.y; \
      }
    LDG(a0,a1,a2,a3, 0)
    LDG(b0,b1,b2,b3, 4)
    for (int d = 0; d < FEAT; d += 8) {
      float2 c0_=a0, c1_=a1, c2_=a2, c3_=a3;
      if (d + 8 < FEAT) { LDG(a0,a1,a2,a3, d+8) }
      FMAS(c0_,c1_,c2_,c3_, d)
      float2 e0_=b0, e1_=b1, e2_=b2, e3_=b3;
      if (d + 12 < FEAT) { LDG(b0,b1,b2,b3, d+12) }
      FMAS(e0_,e1_,e2_,e3_, d+4)
    }
    #undef LDG
    #undef FMAS
  }

  // mask + scale
  float s0[TI], s1[TI];
  #pragma unroll
  for (int r = 0; r < TI; ++r) {
    const int ilim = i0 + r;
    s0[r] = (j0 <= ilim) ? (acc0[r] + c0r[r]) * SCALE : -INFINITY;
    s1[r] = (j1 <= ilim) ? (acc1[r] + c0r[r]) * SCALE : -INFINITY;
  }

  const int lane = t & 63, wv = t >> 6;
  #pragma unroll
  for (int r = 0; r < TI; ++r) {
    const float m = wave_max(fmaxf(s0[r], s1[r]));
    if (lane == 0) redm[wv][r] = m;
  }
  __syncthreads();
  if (t < TI) gm[t] = fmaxf(fmaxf(redm[0][t], redm[1][t]), fmaxf(redm[2][t], redm[3][t]));
  __syncthreads();

  float p0[TI], p1[TI];
  #pragma unroll
  for (int r = 0; r < TI; ++r) {
    p0[r] = __expf(s0[r] - gm[r]);   // -inf -> 0
    p1[r] = __expf(s1[r] - gm[r]);
  }
  if (j0 < jmax) {
    *(float4*)&wT[j0][0] = make_float4(p0[0], p0[1], p0[2], p0[3]);
    *(float4*)&wT[j0][4] = make_float4(p0[4], p0[5], p0[6], p0[7]);
    *(float4*)&wT[j1][0] = make_float4(p1[0], p1[1], p1[2], p1[3]);
    *(float4*)&wT[j1][4] = make_float4(p1[4], p1[5], p1[6], p1[7]);
  }
  #pragma unroll
  for (int r = 0; r < TI; ++r) {
    const float sv = wave_sum(p0[r] + p1[r]);
    if (lane == 0) reds[wv][r] = sv;
  }
  __syncthreads();
  if (t < TI) gs[t] = reds[0][t] + reds[1][t] + reds[2][t] + reds[3][t];

  // PV: group g covers j = g, g+8, ...; each thread owns one e-column
  const int e = t & 31, g = t >> 5;
  float oa[TI];
  #pragma unroll
  for (int r = 0; r < TI; ++r) oa[r] = 0.f;
  const float* Vh = Vmat + (size_t)h*N*E + e;
  for (int j = g; j < jmax; j += 8) {
    const float vv = Vh[j*E];
    const float4 wa = *(const float4*)&wT[j][0];
    const float4 wb = *(const float4*)&wT[j][4];
    oa[0] += wa.x*vv; oa[1] += wa.y*vv; oa[2] += wa.z*vv; oa[3] += wa.w*vv;
    oa[4] += wb.x*vv; oa[5] += wb.y*vv; oa[6] += wb.z*vv; oa[7] += wb.w*vv;
  }
  #pragma unroll
  for (int r = 0; r < TI; ++r) obuf[g][r][e] = oa[r];
  __syncthreads();
  {
    const int r = t >> 5, e2 = t & 31;
    float tot = 0.f;
    #pragma unroll
    for (int g2 = 0; g2 < 8; ++g2) tot += obuf[g2][r][e2];
    out[(i0 + r)*PROJ + h*E + e2] = tot / gs[r];
  }
}

extern "C" void kernel_launch(void* const* d_in, const int* in_sizes, int n_in,
                              void* d_out, int out_size, void* d_ws, size_t ws_size,
                              hipStream_t stream) {
  const float* inp = (const float*)d_in[0];
  const float* pos = (const float*)d_in[1];
  const float* f   = (const float*)d_in[2];
  const float* Wq  = (const float*)d_in[3];
  const float* bq  = (const float*)d_in[4];
  const float* Wk  = (const float*)d_in[5];
  const float* bk  = (const float*)d_in[6];
  const float* Wv  = (const float*)d_in[7];
  const float* bv  = (const float*)d_in[8];
  const float* Wqt = (const float*)d_in[9];
  const float* bqt = (const float*)d_in[10];
  const float* Wt  = (const float*)d_in[11];
  const float* bt  = (const float*)d_in[12];
  float* out = (float*)d_out;

  float* ws    = (float*)d_ws;
  float* WtT   = ws;                       // 128*128          = 16384
  float* Afeat = WtT + PROJ*PROJ;          // H*N*FEAT         = 327680
  float* BT    = Afeat + H*N*FEAT;         // H*FEAT*N         = 327680
  float* Vmat  = BT + H*FEAT*N;            // H*N*E            = 65536
  float* c0    = Vmat + H*N*E;             // H*N              = 2048

  transpose_wt<<<PROJ*PROJ/256, 256, 0, stream>>>(Wt, WtT);
  prep_kernel<<<N/2, 128, 0, stream>>>(inp, pos, f, Wq, bq, Wk, bk, Wv, bv,
                                       Wqt, bqt, WtT, bt, Afeat, BT, Vmat, c0);
  attn_kernel<<<dim3(N/TI, H), 256, 0, stream>>>(Afeat, BT, Vmat, c0, out);
}

// Round 3
// 53.805 us; speedup vs baseline: 1.6270x; 1.1461x over previous
//
#include <hip/hip_runtime.h>
#include <math.h>

namespace {
constexpr int N = 512;
constexpr int DIN = 128;
constexpr int PROJ = 128;
constexpr int H = 4;
constexpr int E = 32;          // per-head dim
constexpr int KF = 64;         // ENC/2 frequencies
constexpr int FEAT = E + 2*KF; // 160 features: [qk | cos/P | sin/Q]
constexpr float SCALE = 0.17677669529663687f; // 1/sqrt(32)
constexpr int TI = 8;          // i-rows per attn block
constexpr int JQ = 4;          // j-chunks
constexpr int CHUNK = 128;     // j per chunk
}

__device__ __forceinline__ float wave_max(float v) {
  #pragma unroll
  for (int o = 32; o > 0; o >>= 1) v = fmaxf(v, __shfl_xor(v, o, 64));
  return v;
}
__device__ __forceinline__ float wave_sum(float v) {
  #pragma unroll
  for (int o = 32; o > 0; o >>= 1) v += __shfl_xor(v, o, 64);
  return v;
}

// ---- kernel 0: transpose Wt (128x128) so prep's u-matvec reads coalesced ----
__global__ __launch_bounds__(256)
void transpose_wt(const float* __restrict__ Wt, float* __restrict__ WtT) {
  const int idx = blockIdx.x * 256 + threadIdx.x;   // 0..16383
  const int c = idx >> 7, p = idx & 127;            // read Wt[c][p] coalesced
  WtT[p * PROJ + c] = Wt[idx];
}

// ---- kernel 1: per-row features. 2 rows/block, 256 threads (d-split) ----
__global__ __launch_bounds__(256)
void prep_kernel(const float* __restrict__ inp, const float* __restrict__ pos,
                 const float* __restrict__ f,
                 const float* __restrict__ Wq, const float* __restrict__ bq,
                 const float* __restrict__ Wk, const float* __restrict__ bk,
                 const float* __restrict__ Wv, const float* __restrict__ bv,
                 const float* __restrict__ Wqt, const float* __restrict__ bqt,
                 const float* __restrict__ WtT, const float* __restrict__ bt,
                 float* __restrict__ Afeat, float* __restrict__ BT,
                 float* __restrict__ Vmat, float* __restrict__ c0)
{
  const int i0 = blockIdx.x * 2;
  const int t = threadIdx.x;            // 0..255
  const int c = t & 127, dh = t >> 7;   // output col, d-half
  __shared__ float x[2][DIN];
  __shared__ float qt_l[2][PROJ];
  __shared__ float ss[2][KF], sc[2][KF];
  __shared__ float u_l[2][H][PROJ];
  __shared__ float part[2][4][2][128];  // [dh][mat][row][col] 8KB

  x[t >> 7][t & 127] = inp[(i0 + (t >> 7)) * DIN + (t & 127)];
  if (t < 128) {
    const int r = t >> 6, k = t & 63;
    float s_, c_;
    sincosf(pos[i0 + r] * f[k], &s_, &c_);
    ss[r][k] = s_; sc[r][k] = c_;
  }
  __syncthreads();

  // partial projections over this thread's d-half
  float aq0=0.f, aq1=0.f, ak0=0.f, ak1=0.f, av0=0.f, av1=0.f, at0=0.f, at1=0.f;
  const int dbeg = dh * 64;
  #pragma unroll 4
  for (int dd = 0; dd < 64; ++dd) {
    const int d = dbeg + dd;
    const float x0 = x[0][d], x1 = x[1][d];
    const float wq = Wq [d*PROJ + c], wk = Wk [d*PROJ + c];
    const float wv = Wv [d*PROJ + c], wt = Wqt[d*PROJ + c];
    aq0 += x0*wq; aq1 += x1*wq;
    ak0 += x0*wk; ak1 += x1*wk;
    av0 += x0*wv; av1 += x1*wv;
    at0 += x0*wt; at1 += x1*wt;
  }
  part[dh][0][0][c]=aq0; part[dh][0][1][c]=aq1;
  part[dh][1][0][c]=ak0; part[dh][1][1][c]=ak1;
  part[dh][2][0][c]=av0; part[dh][2][1][c]=av1;
  part[dh][3][0][c]=at0; part[dh][3][1][c]=at1;
  __syncthreads();

  if (t < 128) {
    const int h = t >> 5, e = t & 31;
    const float q0 = part[0][0][0][c] + part[1][0][0][c] + bq[c];
    const float q1 = part[0][0][1][c] + part[1][0][1][c] + bq[c];
    const float k0 = part[0][1][0][c] + part[1][1][0][c] + bk[c];
    const float k1 = part[0][1][1][c] + part[1][1][1][c] + bk[c];
    const float v0 = part[0][2][0][c] + part[1][2][0][c] + bv[c];
    const float v1 = part[0][2][1][c] + part[1][2][1][c] + bv[c];
    const float t0 = part[0][3][0][c] + part[1][3][0][c] + bqt[c];
    const float t1 = part[0][3][1][c] + part[1][3][1][c] + bqt[c];
    Afeat[(h*N + i0    )*FEAT + e] = q0;
    Afeat[(h*N + i0 + 1)*FEAT + e] = q1;
    BT[(size_t)(h*FEAT + e)*N + i0    ] = k0;
    BT[(size_t)(h*FEAT + e)*N + i0 + 1] = k1;
    Vmat[(h*N + i0    )*E + e] = v0;
    Vmat[(h*N + i0 + 1)*E + e] = v1;
    qt_l[0][c] = t0; qt_l[1][c] = t1;
  }
  __syncthreads();

  // u[r][hh][c] = sum_e WtT[hh*E+e][c] * qt[r][hh*E+e]
  {
    const int g = t >> 7;  // 0,1
    for (int hh = g; hh < H; hh += 2) {
      float u0 = 0.f, u1 = 0.f;
      #pragma unroll 8
      for (int e2 = 0; e2 < E; ++e2) {
        const float w = WtT[(hh*E + e2)*PROJ + c];
        u0 += w * qt_l[0][hh*E + e2];
        u1 += w * qt_l[1][hh*E + e2];
      }
      u_l[0][hh][c] = u0; u_l[1][hh][c] = u1;
    }
  }
  if (t < 8) {  // c0[h,i] = bt[h*E:]·qt[h*E:]
    const int r = t >> 2, hh = t & 3;
    float acc = 0.f;
    for (int e2 = 0; e2 < E; ++e2) acc += bt[hh*E + e2] * qt_l[r][hh*E + e2];
    c0[hh*N + i0 + r] = acc;
  }
  __syncthreads();

  // A-side P/Q features + B-side trig features
  {
    const int k = t & 63, half = (t >> 6) & 1, r = t >> 7;
    #pragma unroll
    for (int hh = half; hh < H; hh += 2) {
      const float u0 = u_l[r][hh][2*k], u1 = u_l[r][hh][2*k + 1];
      Afeat[(hh*N + i0 + r)*FEAT + E + k]      =  u0*ss[r][k] + u1*sc[r][k];
      Afeat[(hh*N + i0 + r)*FEAT + E + KF + k] = -u0*sc[r][k] + u1*ss[r][k];
      BT[(size_t)(hh*FEAT + E + k)*N      + i0 + r] = sc[r][k];
      BT[(size_t)(hh*FEAT + E + KF + k)*N + i0 + r] = ss[r][k];
    }
  }
}

// ---- kernel 2: flash-style partial attention over a 128-j chunk ----
__global__ __launch_bounds__(256)
void attn_partial(const float* __restrict__ Afeat, const float* __restrict__ BT,
                  const float* __restrict__ Vmat, const float* __restrict__ c0,
                  float* __restrict__ Po, float* __restrict__ Pm,
                  float* __restrict__ Ps)
{
  const int b = blockIdx.x, h = blockIdx.y, q = blockIdx.z;
  const int i0 = b * TI, jbase = q * CHUNK;
  if (jbase > i0) return;   // chunk entirely above diagonal for all 8 rows
  const int t = threadIdx.x;
  const int jp = t & 63;                                   // j-pair lane
  const int rh = __builtin_amdgcn_readfirstlane(t >> 6);   // wave id 0..3 -> rows rh*2, rh*2+1

  __shared__ float pT[CHUNK][12];     // [j][row] padded, 6KB
  __shared__ float obuf[16][TI][32];  // 16KB

  const float* Arow = Afeat + (size_t)(h*N + i0 + rh*2)*FEAT;  // wave-uniform -> s_load
  const float* Bh   = BT + (size_t)h*FEAT*N + jbase + 2*jp;
  const float cc0 = c0[h*N + i0 + rh*2];
  const float cc1 = c0[h*N + i0 + rh*2 + 1];

  float acc00=0.f, acc01=0.f, acc10=0.f, acc11=0.f;  // [row][jj]
  #pragma unroll 8
  for (int d = 0; d < FEAT; d += 4) {
    const float2 b0 = *(const float2*)&Bh[(size_t)(d+0)*N];
    const float2 b1 = *(const float2*)&Bh[(size_t)(d+1)*N];
    const float2 b2 = *(const float2*)&Bh[(size_t)(d+2)*N];
    const float2 b3 = *(const float2*)&Bh[(size_t)(d+3)*N];
    const float4 a0 = *(const float4*)&Arow[d];          // uniform
    const float4 a1 = *(const float4*)&Arow[FEAT + d];   // uniform
    acc00 += a0.x*b0.x + a0.y*b1.x + a0.z*b2.x + a0.w*b3.x;
    acc01 += a0.x*b0.y + a0.y*b1.y + a0.z*b2.y + a0.w*b3.y;
    acc10 += a1.x*b0.x + a1.y*b1.x + a1.z*b2.x + a1.w*b3.x;
    acc11 += a1.x*b0.y + a1.y*b1.y + a1.z*b2.y + a1.w*b3.y;
  }

  const int i_0 = i0 + rh*2, i_1 = i_0 + 1;
  const int j0 = jbase + 2*jp, j1 = j0 + 1;
  const float s00 = (j0 <= i_0) ? (acc00 + cc0)*SCALE : -INFINITY;
  const float s01 = (j1 <= i_0) ? (acc01 + cc0)*SCALE : -INFINITY;
  const float s10 = (j0 <= i_1) ? (acc10 + cc1)*SCALE : -INFINITY;
  const float s11 = (j1 <= i_1) ? (acc11 + cc1)*SCALE : -INFINITY;

  const float m0 = wave_max(fmaxf(s00, s01));
  const float m1 = wave_max(fmaxf(s10, s11));
  const float p00 = __expf(s00 - m0), p01 = __expf(s01 - m0);
  const float p10 = __expf(s10 - m1), p11 = __expf(s11 - m1);
  const float sum0 = wave_sum(p00 + p01);
  const float sum1 = wave_sum(p10 + p11);

  *(float2*)&pT[2*jp    ][rh*2] = make_float2(p00, p10);
  *(float2*)&pT[2*jp + 1][rh*2] = make_float2(p01, p11);
  if ((t & 63) == 0) {
    const int base = (h*N + i_0)*JQ + q;
    Pm[base]      = m0; Ps[base]      = sum0;
    Pm[base + JQ] = m1; Ps[base + JQ] = sum1;
  }
  __syncthreads();

  // PV: thread owns e-pair e2, group g covers jl = g, g+16, ...
  const int e2 = (t & 15)*2, g = t >> 4;
  float2 o[TI];
  #pragma unroll
  for (int r = 0; r < TI; ++r) o[r] = make_float2(0.f, 0.f);
  const float* Vh = Vmat + ((size_t)h*N + jbase)*E + e2;
  #pragma unroll
  for (int it = 0; it < CHUNK/16; ++it) {
    const int jl = g + 16*it;
    const float2 vv = *(const float2*)&Vh[jl*E];
    const float4 pa = *(const float4*)&pT[jl][0];
    const float4 pb = *(const float4*)&pT[jl][4];
    o[0].x += pa.x*vv.x; o[0].y += pa.x*vv.y;
    o[1].x += pa.y*vv.x; o[1].y += pa.y*vv.y;
    o[2].x += pa.z*vv.x; o[2].y += pa.z*vv.y;
    o[3].x += pa.w*vv.x; o[3].y += pa.w*vv.y;
    o[4].x += pb.x*vv.x; o[4].y += pb.x*vv.y;
    o[5].x += pb.y*vv.x; o[5].y += pb.y*vv.y;
    o[6].x += pb.z*vv.x; o[6].y += pb.z*vv.y;
    o[7].x += pb.w*vv.x; o[7].y += pb.w*vv.y;
  }
  #pragma unroll
  for (int r = 0; r < TI; ++r) *(float2*)&obuf[g][r][e2] = o[r];
  __syncthreads();
  {
    const int r = t >> 5, e = t & 31;
    float tot = 0.f;
    #pragma unroll
    for (int g2 = 0; g2 < 16; ++g2) tot += obuf[g2][r][e];
    Po[((size_t)(h*N + i0 + r)*JQ + q)*E + e] = tot;
  }
}

// ---- kernel 3: combine partials (exact softmax merge) ----
__global__ __launch_bounds__(256)
void attn_combine(const float* __restrict__ Po, const float* __restrict__ Pm,
                  const float* __restrict__ Ps, float* __restrict__ out)
{
  const int gid = blockIdx.x * 256 + threadIdx.x;   // 0..65535
  const int task = gid >> 5, e = gid & 31;          // task = h*N + i
  const int h = task >> 9, i = task & (N - 1);
  const int nq = (i >> 7) + 1;
  float m = -INFINITY;
  for (int qq = 0; qq < nq; ++qq) m = fmaxf(m, Pm[task*JQ + qq]);
  float s = 0.f, o = 0.f;
  for (int qq = 0; qq < nq; ++qq) {
    const float w = __expf(Pm[task*JQ + qq] - m);
    s += Ps[task*JQ + qq] * w;
    o += Po[(size_t)(task*JQ + qq)*E + e] * w;
  }
  out[i*PROJ + h*E + e] = o / s;
}

extern "C" void kernel_launch(void* const* d_in, const int* in_sizes, int n_in,
                              void* d_out, int out_size, void* d_ws, size_t ws_size,
                              hipStream_t stream) {
  const float* inp = (const float*)d_in[0];
  const float* pos = (const float*)d_in[1];
  const float* f   = (const float*)d_in[2];
  const float* Wq  = (const float*)d_in[3];
  const float* bq  = (const float*)d_in[4];
  const float* Wk  = (const float*)d_in[5];
  const float* bk  = (const float*)d_in[6];
  const float* Wv  = (const float*)d_in[7];
  const float* bv  = (const float*)d_in[8];
  const float* Wqt = (const float*)d_in[9];
  const float* bqt = (const float*)d_in[10];
  const float* Wt  = (const float*)d_in[11];
  const float* bt  = (const float*)d_in[12];
  float* out = (float*)d_out;

  float* ws    = (float*)d_ws;
  float* WtT   = ws;                       // 16384
  float* Afeat = WtT + PROJ*PROJ;          // H*N*FEAT = 327680
  float* BT    = Afeat + H*N*FEAT;         // 327680
  float* Vmat  = BT + (size_t)H*FEAT*N;    // 65536
  float* c0    = Vmat + H*N*E;             // 2048
  float* Po    = c0 + H*N;                 // H*N*JQ*E = 262144
  float* Pm    = Po + (size_t)H*N*JQ*E;    // 8192
  float* Ps    = Pm + H*N*JQ;              // 8192

  transpose_wt<<<PROJ*PROJ/256, 256, 0, stream>>>(Wt, WtT);
  prep_kernel<<<N/2, 256, 0, stream>>>(inp, pos, f, Wq, bq, Wk, bk, Wv, bv,
                                       Wqt, bqt, WtT, bt, Afeat, BT, Vmat, c0);
  attn_partial<<<dim3(N/TI, H, JQ), 256, 0, stream>>>(Afeat, BT, Vmat, c0, Po, Pm, Ps);
  attn_combine<<<H*N*E/256, 256, 0, stream>>>(Po, Pm, Ps, out);
}

// Round 4
// 30.885 us; speedup vs baseline: 2.8345x; 1.7421x over previous
//
#include <hip/hip_runtime.h>
#include <math.h>

namespace {
constexpr int N = 512;
constexpr int DIN = 128;
constexpr int PROJ = 128;
constexpr int H = 4;
constexpr int E = 32;          // per-head dim
constexpr int KF = 64;         // ENC/2 frequencies
constexpr int FEAT = E + 2*KF; // 160 A-features per head: [q | P | Q]
constexpr float SCALE = 0.17677669529663687f; // 1/sqrt(32)
constexpr int TI = 8;          // i-rows per attn block
constexpr int JQ = 8;          // j-chunks
constexpr int CHUNK = 64;      // j per chunk
}

__device__ __forceinline__ float wave_max(float v) {
  #pragma unroll
  for (int o = 32; o > 0; o >>= 1) v = fmaxf(v, __shfl_xor(v, o, 64));
  return v;
}
__device__ __forceinline__ float wave_sum(float v) {
  #pragma unroll
  for (int o = 32; o > 0; o >>= 1) v += __shfl_xor(v, o, 64);
  return v;
}

// ---- kernel 1: projections (4 matrices) + Wt transpose in spare blocks ----
// blocks 0..511: rowTile = bx & 127 (4 rows each), mat = bx >> 7
// blocks 512..543: transpose Wt -> WtT
__global__ __launch_bounds__(256)
void proj_kernel(const float* __restrict__ inp,
                 const float* __restrict__ Wq, const float* __restrict__ bq,
                 const float* __restrict__ Wk, const float* __restrict__ bk,
                 const float* __restrict__ Wv, const float* __restrict__ bv,
                 const float* __restrict__ Wqt, const float* __restrict__ bqt,
                 const float* __restrict__ Wt, float* __restrict__ WtT,
                 float* __restrict__ Afeat, float* __restrict__ BTk,
                 float* __restrict__ Vmat, float* __restrict__ qtbuf)
{
  const int bx = blockIdx.x;
  const int t = threadIdx.x;
  if (bx >= 512) {  // Wt transpose: 32 blocks x 512 elems
    const int base = (bx - 512) * 512 + t;
    #pragma unroll
    for (int r = 0; r < 2; ++r) {
      const int id = base + r * 256;
      WtT[(id & 127) * PROJ + (id >> 7)] = Wt[id];
    }
    return;
  }
  const int rowTile = bx & 127, mat = bx >> 7;
  const int i0 = rowTile * 4;
  const int c = t & 127, half = t >> 7;
  __shared__ float x[4][DIN];
  #pragma unroll
  for (int r = 0; r < 2; ++r) {
    const int id = t + r * 256;
    x[id >> 7][id & 127] = inp[i0 * DIN + id];
  }
  const float* W; const float* bvec;
  switch (mat) {
    case 0:  W = Wq;  bvec = bq;  break;
    case 1:  W = Wk;  bvec = bk;  break;
    case 2:  W = Wv;  bvec = bv;  break;
    default: W = Wqt; bvec = bqt; break;
  }
  __syncthreads();

  const int r0 = half * 2, r1 = r0 + 1;
  float a0 = 0.f, a1 = 0.f;
  #pragma unroll 8
  for (int d = 0; d < DIN; d += 2) {
    const float w0 = W[d * PROJ + c];
    const float w1 = W[(d + 1) * PROJ + c];
    const float2 x0 = *(const float2*)&x[r0][d];
    const float2 x1 = *(const float2*)&x[r1][d];
    a0 += w0 * x0.x + w1 * x0.y;
    a1 += w0 * x1.x + w1 * x1.y;
  }
  const float bb = bvec[c];
  a0 += bb; a1 += bb;
  const int h = c >> 5, e = c & 31;
  const int row0 = i0 + r0, row1 = i0 + r1;
  if (mat == 0) {
    Afeat[(h * N + row0) * FEAT + e] = a0;
    Afeat[(h * N + row1) * FEAT + e] = a1;
  } else if (mat == 1) {
    BTk[(size_t)(h * E + e) * N + row0] = a0;
    BTk[(size_t)(h * E + e) * N + row1] = a1;
  } else if (mat == 2) {
    Vmat[(h * N + row0) * E + e] = a0;
    Vmat[(h * N + row1) * E + e] = a1;
  } else {
    qtbuf[row0 * PROJ + c] = a0;
    qtbuf[row1 * PROJ + c] = a1;
  }
}

// ---- kernel 2: per-row features (u, A P/Q, shared trig, c0). 1 row/block ----
__global__ __launch_bounds__(256)
void feat_kernel(const float* __restrict__ pos, const float* __restrict__ f,
                 const float* __restrict__ qtbuf, const float* __restrict__ WtT,
                 const float* __restrict__ bt,
                 float* __restrict__ Afeat, float* __restrict__ Btrig,
                 float* __restrict__ c0)
{
  const int i = blockIdx.x;
  const int t = threadIdx.x;
  __shared__ float qtl[PROJ];
  __shared__ float ss[KF], sc[KF];
  __shared__ float ul[H][PROJ];

  if (t < PROJ) {
    qtl[t] = qtbuf[i * PROJ + t];
  } else if (t < PROJ + KF) {
    const int k = t - PROJ;
    float s_, c_;
    sincosf(pos[i] * f[k], &s_, &c_);
    ss[k] = s_; sc[k] = c_;
  }
  __syncthreads();

  // u[h][c] = sum_e WtT[h*E+e][c] * qt[h*E+e]
  {
    const int c = t & 127, g = t >> 7;
    #pragma unroll
    for (int h = g; h < H; h += 2) {
      float u = 0.f;
      #pragma unroll 8
      for (int e = 0; e < E; ++e)
        u += WtT[(h * E + e) * PROJ + c] * qtl[h * E + e];
      ul[h][c] = u;
    }
  }
  if (t < H) {  // c0[h,i] = bt[h*E:]·qt[h*E:]
    float acc = 0.f;
    for (int e = 0; e < E; ++e) acc += bt[t * E + e] * qtl[t * E + e];
    c0[t * N + i] = acc;
  }
  __syncthreads();

  const int k = t & 63, h = t >> 6;
  const float u0 = ul[h][2 * k], u1 = ul[h][2 * k + 1];
  const float s_ = ss[k], c_ = sc[k];
  Afeat[(h * N + i) * FEAT + E + k]      =  u0 * s_ + u1 * c_;  // pairs with cos_j
  Afeat[(h * N + i) * FEAT + E + KF + k] = -u0 * c_ + u1 * s_;  // pairs with sin_j
  if (h == 0) {
    Btrig[k * N + i]        = c_;
    Btrig[(KF + k) * N + i] = s_;
  }
}

// ---- kernel 3: flash-style partial attention over a 64-j chunk ----
__global__ __launch_bounds__(256)
void attn_partial(const float* __restrict__ Afeat, const float* __restrict__ BTk,
                  const float* __restrict__ Btrig, const float* __restrict__ Vmat,
                  const float* __restrict__ c0,
                  float* __restrict__ Po, float* __restrict__ Pm,
                  float* __restrict__ Ps)
{
  const int b = blockIdx.x, h = blockIdx.y, q = blockIdx.z;
  const int i0 = b * TI, jbase = q * CHUNK;
  if (jbase > i0) return;   // chunk entirely above diagonal
  const int t = threadIdx.x;
  const int lane = t & 63;
  const int rh = __builtin_amdgcn_readfirstlane(t >> 6);  // wave -> rows 2rh, 2rh+1
  const int j = jbase + lane;

  __shared__ float pT[CHUNK][12];     // [j][row] padded
  __shared__ float obuf[16][TI][32];

  const float* A0 = Afeat + (size_t)(h * N + i0 + rh * 2) * FEAT;  // wave-uniform
  const float* A1 = A0 + FEAT;
  const float cc0 = c0[h * N + i0 + rh * 2];
  const float cc1 = c0[h * N + i0 + rh * 2 + 1];

  float acc0 = 0.f, acc1 = 0.f;
  {
    const float* Bp = BTk + (size_t)h * E * N + j;
    #pragma unroll
    for (int d = 0; d < E; d += 4) {
      const float b0 = Bp[(size_t)(d + 0) * N];
      const float b1 = Bp[(size_t)(d + 1) * N];
      const float b2 = Bp[(size_t)(d + 2) * N];
      const float b3 = Bp[(size_t)(d + 3) * N];
      const float4 a0 = *(const float4*)&A0[d];
      const float4 a1 = *(const float4*)&A1[d];
      acc0 += a0.x * b0 + a0.y * b1 + a0.z * b2 + a0.w * b3;
      acc1 += a1.x * b0 + a1.y * b1 + a1.z * b2 + a1.w * b3;
    }
  }
  {
    const float* Bp = Btrig + j;
    #pragma unroll 8
    for (int d = 0; d < 2 * KF; d += 4) {
      const float b0 = Bp[(size_t)(d + 0) * N];
      const float b1 = Bp[(size_t)(d + 1) * N];
      const float b2 = Bp[(size_t)(d + 2) * N];
      const float b3 = Bp[(size_t)(d + 3) * N];
      const float4 a0 = *(const float4*)&A0[E + d];
      const float4 a1 = *(const float4*)&A1[E + d];
      acc0 += a0.x * b0 + a0.y * b1 + a0.z * b2 + a0.w * b3;
      acc1 += a1.x * b0 + a1.y * b1 + a1.z * b2 + a1.w * b3;
    }
  }

  const int i_0 = i0 + rh * 2, i_1 = i_0 + 1;
  const float s0 = (j <= i_0) ? (acc0 + cc0) * SCALE : -INFINITY;
  const float s1 = (j <= i_1) ? (acc1 + cc1) * SCALE : -INFINITY;

  const float m0 = wave_max(s0);
  const float m1 = wave_max(s1);
  const float p0 = __expf(s0 - m0);
  const float p1 = __expf(s1 - m1);
  const float sum0 = wave_sum(p0);
  const float sum1 = wave_sum(p1);

  *(float2*)&pT[lane][rh * 2] = make_float2(p0, p1);
  if (lane == 0) {
    const int base = (h * N + i_0) * JQ + q;
    Pm[base]      = m0; Ps[base]      = sum0;
    Pm[base + JQ] = m1; Ps[base + JQ] = sum1;
  }
  __syncthreads();

  // PV: thread owns e-pair, group gg covers jl = gg, gg+16, ...
  const int e2 = (t & 15) * 2, gg = t >> 4;
  float2 o[TI];
  #pragma unroll
  for (int r = 0; r < TI; ++r) o[r] = make_float2(0.f, 0.f);
  const float* Vh = Vmat + ((size_t)h * N + jbase) * E + e2;
  #pragma unroll
  for (int it = 0; it < CHUNK / 16; ++it) {
    const int jl = gg + 16 * it;
    const float2 vv = *(const float2*)&Vh[jl * E];
    const float4 pa = *(const float4*)&pT[jl][0];
    const float4 pb = *(const float4*)&pT[jl][4];
    o[0].x += pa.x * vv.x; o[0].y += pa.x * vv.y;
    o[1].x += pa.y * vv.x; o[1].y += pa.y * vv.y;
    o[2].x += pa.z * vv.x; o[2].y += pa.z * vv.y;
    o[3].x += pa.w * vv.x; o[3].y += pa.w * vv.y;
    o[4].x += pb.x * vv.x; o[4].y += pb.x * vv.y;
    o[5].x += pb.y * vv.x; o[5].y += pb.y * vv.y;
    o[6].x += pb.z * vv.x; o[6].y += pb.z * vv.y;
    o[7].x += pb.w * vv.x; o[7].y += pb.w * vv.y;
  }
  #pragma unroll
  for (int r = 0; r < TI; ++r) *(float2*)&obuf[gg][r][e2] = o[r];
  __syncthreads();
  {
    const int r = t >> 5, e = t & 31;
    float tot = 0.f;
    #pragma unroll
    for (int g2 = 0; g2 < 16; ++g2) tot += obuf[g2][r][e];
    Po[((size_t)(h * N + i0 + r) * JQ + q) * E + e] = tot;
  }
}

// ---- kernel 4: combine partials (exact softmax merge) ----
__global__ __launch_bounds__(256)
void attn_combine(const float* __restrict__ Po, const float* __restrict__ Pm,
                  const float* __restrict__ Ps, float* __restrict__ out)
{
  const int gid = blockIdx.x * 256 + threadIdx.x;   // 0..65535
  const int task = gid >> 5, e = gid & 31;          // task = h*N + i
  const int h = task >> 9, i = task & (N - 1);
  const int nq = (i >> 6) + 1;
  float m = -INFINITY;
  for (int qq = 0; qq < nq; ++qq) m = fmaxf(m, Pm[task * JQ + qq]);
  float s = 0.f, o = 0.f;
  for (int qq = 0; qq < nq; ++qq) {
    const float w = __expf(Pm[task * JQ + qq] - m);
    s += Ps[task * JQ + qq] * w;
    o += Po[(size_t)(task * JQ + qq) * E + e] * w;
  }
  out[i * PROJ + h * E + e] = o / s;
}

extern "C" void kernel_launch(void* const* d_in, const int* in_sizes, int n_in,
                              void* d_out, int out_size, void* d_ws, size_t ws_size,
                              hipStream_t stream) {
  const float* inp = (const float*)d_in[0];
  const float* pos = (const float*)d_in[1];
  const float* f   = (const float*)d_in[2];
  const float* Wq  = (const float*)d_in[3];
  const float* bq  = (const float*)d_in[4];
  const float* Wk  = (const float*)d_in[5];
  const float* bk  = (const float*)d_in[6];
  const float* Wv  = (const float*)d_in[7];
  const float* bv  = (const float*)d_in[8];
  const float* Wqt = (const float*)d_in[9];
  const float* bqt = (const float*)d_in[10];
  const float* Wt  = (const float*)d_in[11];
  const float* bt  = (const float*)d_in[12];
  float* out = (float*)d_out;

  float* ws    = (float*)d_ws;
  float* WtT   = ws;                          // 16384
  float* Afeat = WtT + PROJ * PROJ;           // H*N*FEAT   = 327680
  float* BTk   = Afeat + H * N * FEAT;        // H*E*N      = 65536
  float* Btrig = BTk + (size_t)H * E * N;     // 2*KF*N     = 65536
  float* Vmat  = Btrig + 2 * KF * N;          // H*N*E      = 65536
  float* qtbuf = Vmat + H * N * E;            // N*PROJ     = 65536
  float* c0    = qtbuf + N * PROJ;            // H*N        = 2048
  float* Po    = c0 + H * N;                  // H*N*JQ*E   = 524288
  float* Pm    = Po + (size_t)H * N * JQ * E; // H*N*JQ     = 16384
  float* Ps    = Pm + H * N * JQ;             // 16384

  proj_kernel<<<544, 256, 0, stream>>>(inp, Wq, bq, Wk, bk, Wv, bv, Wqt, bqt,
                                       Wt, WtT, Afeat, BTk, Vmat, qtbuf);
  feat_kernel<<<N, 256, 0, stream>>>(pos, f, qtbuf, WtT, bt, Afeat, Btrig, c0);
  attn_partial<<<dim3(N / TI, H, JQ), 256, 0, stream>>>(Afeat, BTk, Btrig, Vmat,
                                                        c0, Po, Pm, Ps);
  attn_combine<<<H * N * E / 256, 256, 0, stream>>>(Po, Pm, Ps, out);
}